// Round 2
// baseline (187.502 us; speedup 1.0000x reference)
//
#include <hip/hip_runtime.h>

// ANOVA kernel order 3:  out[b] = sum_e e3(x[b, :, e])
// x: (8192, 64, 64) fp32, row-major, e innermost.
//
// R2 design: one wave (64 lanes) per batch row.
//   lane = g + 16*h;  g in [0,16) = float4 column group, h in [0,4) = field segment.
//   Each thread runs the ESP DP over its 16 fields for its 4 embedding columns,
//   then segments are merged across h with the ESP union identity
//   e_k(A∪B) = sum_{i+j=k} e_i(A) e_j(B) via shfl_xor(16), shfl_xor(32),
//   then e3 is summed over components and over g (shfl_xor 1,2,4,8).
// Grid: 8192 waves -> 2048 blocks of 256 = 8 blocks/CU = 32 waves/CU (max occ).
// Memory-bound: 128 MiB read once -> floor ~21 us at 6.3 TB/s.

constexpr int BATCH = 8192;

__device__ inline float4 shfl_xor4(float4 v, int d) {
    float4 r;
    r.x = __shfl_xor(v.x, d);
    r.y = __shfl_xor(v.y, d);
    r.z = __shfl_xor(v.z, d);
    r.w = __shfl_xor(v.w, d);
    return r;
}

__global__ __launch_bounds__(256) void anova3_kernel(const float* __restrict__ x,
                                                     float* __restrict__ out) {
    const int tid  = blockIdx.x * 256 + threadIdx.x;
    const int lane = threadIdx.x & 63;
    const int b    = tid >> 6;        // one wave per batch row
    const int g    = lane & 15;       // float4 group within 64-wide embedding
    const int h    = lane >> 4;       // field segment [0,4)

    // float4 units: row = 1024, field = 16. Segment h covers fields [16h, 16h+16).
    const float4* xp = reinterpret_cast<const float4*>(x)
                     + (size_t)b * 1024 + (size_t)h * 256 + g;

    float4 s1 = make_float4(0.f, 0.f, 0.f, 0.f);
    float4 s2 = s1, s3 = s1;

#pragma unroll
    for (int f = 0; f < 16; ++f) {
        float4 v = xp[f * 16];
        // order matters: s3 uses old s2, s2 uses old s1
        s3.x = fmaf(s2.x, v.x, s3.x); s2.x = fmaf(s1.x, v.x, s2.x); s1.x += v.x;
        s3.y = fmaf(s2.y, v.y, s3.y); s2.y = fmaf(s1.y, v.y, s2.y); s1.y += v.y;
        s3.z = fmaf(s2.z, v.z, s3.z); s2.z = fmaf(s1.z, v.z, s2.z); s1.z += v.z;
        s3.w = fmaf(s2.w, v.w, s3.w); s2.w = fmaf(s1.w, v.w, s2.w); s1.w += v.w;
    }

    // Merge field segments across h (lane distances 16 then 32).
    // Symmetric union merge: both partners compute the same merged ESPs.
#pragma unroll
    for (int d = 16; d <= 32; d <<= 1) {
        float4 o1 = shfl_xor4(s1, d);
        float4 o2 = shfl_xor4(s2, d);
        float4 o3 = shfl_xor4(s3, d);
        // e3' = e3A + e3B + e2A*e1B + e1A*e2B   (uses old s1,s2)
        s3.x += o3.x + s2.x * o1.x + s1.x * o2.x;
        s3.y += o3.y + s2.y * o1.y + s1.y * o2.y;
        s3.z += o3.z + s2.z * o1.z + s1.z * o2.z;
        s3.w += o3.w + s2.w * o1.w + s1.w * o2.w;
        // e2' = e2A + e2B + e1A*e1B
        s2.x += o2.x + s1.x * o1.x;
        s2.y += o2.y + s1.y * o1.y;
        s2.z += o2.z + s1.z * o1.z;
        s2.w += o2.w + s1.w * o1.w;
        // e1' = e1A + e1B
        s1.x += o1.x; s1.y += o1.y; s1.z += o1.z; s1.w += o1.w;
    }

    // Sum e3 over the 4 components, then over the 16 g-groups (lane bits 0..3).
    float r = (s3.x + s3.y) + (s3.z + s3.w);
    r += __shfl_xor(r, 1);
    r += __shfl_xor(r, 2);
    r += __shfl_xor(r, 4);
    r += __shfl_xor(r, 8);

    if (lane == 0) out[b] = r;
}

extern "C" void kernel_launch(void* const* d_in, const int* in_sizes, int n_in,
                              void* d_out, int out_size, void* d_ws, size_t ws_size,
                              hipStream_t stream) {
    const float* x = (const float*)d_in[0];
    float* out = (float*)d_out;
    const int total_threads = BATCH * 64;   // one wave per row
    dim3 grid(total_threads / 256);         // 2048 blocks
    anova3_kernel<<<grid, dim3(256), 0, stream>>>(x, out);
}